// Round 2
// baseline (157.532 us; speedup 1.0000x reference)
//
#include <hip/hip_runtime.h>
#include <hip/hip_bf16.h>
#include <stdint.h>
#include <stddef.h>

// NT-Xent loss, B=4096, D=256, N=8192, T=0.5.
// normalize(+zero sumexp) -> fused ZZ^T GEMM + exp row-sum + positive capture
// -> 1-block finalize/mean. No NxN materialization.

#define B_ROWS 4096
#define D_DIM  256
#define N_ROWS 8192
#define BM 128
#define BN 128
#define BK 64

typedef __bf16 bf16;
typedef bf16  bf16x8  __attribute__((ext_vector_type(8)));
typedef bf16  bf16x4  __attribute__((ext_vector_type(4)));
typedef float floatx4 __attribute__((ext_vector_type(4)));

// ---------------------------------------------------------------- normalize
// One wave per row: 256 fp32 -> L2-normalized bf16. Also zeroes sumexp[row].
__global__ __launch_bounds__(256) void normalize_kernel(
    const float* __restrict__ z_i, const float* __restrict__ z_j,
    bf16* __restrict__ zn, float* __restrict__ sumexp) {
  const int wave = threadIdx.x >> 6;
  const int lane = threadIdx.x & 63;
  const int row  = blockIdx.x * 4 + wave;
  const float* src = (row < B_ROWS) ? (z_i + (size_t)row * D_DIM)
                                    : (z_j + (size_t)(row - B_ROWS) * D_DIM);
  float4 v = ((const float4*)src)[lane];
  float ss = v.x * v.x + v.y * v.y + v.z * v.z + v.w * v.w;
  #pragma unroll
  for (int m = 1; m < 64; m <<= 1) ss += __shfl_xor(ss, m);
  const float rn = rsqrtf(ss);
  bf16x4 o;
  o[0] = (bf16)(v.x * rn);
  o[1] = (bf16)(v.y * rn);
  o[2] = (bf16)(v.z * rn);
  o[3] = (bf16)(v.w * rn);
  ((bf16x4*)(zn + (size_t)row * D_DIM))[lane] = o;
  if (lane == 0) sumexp[row] = 0.f;
}

// ------------------------------------------------------- fused sim+exp+sum
// Grid: 64 row-tiles x 32 col-chunks (2 j-tiles each) = 2048 blocks.
// 128x128 tile, 4 waves (2x2), 4x4 frags of 16x16x32 bf16 MFMA, BK=64,
// global_load_lds width=16 with XOR-swizzled LDS layout (bank-conflict-free):
// chunk (m, kc) of 8 bf16 lives at slot m*8 + (kc ^ (m&7)). The swizzle is
// applied on the GLOBAL source address (dest is forced to base+lane*16).
// Epilogue: e = exp(2*sim) (self-diag -> 0), positive pairs (|ri-jt|==32,
// local diagonal) stored to pos[] (single writer).
__global__ __launch_bounds__(256, 4) void simexp_kernel(
    const bf16* __restrict__ zn, float* __restrict__ sumexp,
    float* __restrict__ pos) {
  __shared__ __align__(16) bf16 As[BM * BK];
  __shared__ __align__(16) bf16 Bs[BN * BK];

  const int tid   = threadIdx.x;
  const int wave  = tid >> 6;
  const int lane  = tid & 63;
  const int lcol  = lane & 15;   // MFMA: A row / B col / C col
  const int lquad = lane >> 4;   // MFMA: k-group / C row-group
  const int sw    = lcol & 7;    // read-side swizzle key (== m&7)
  const int wr = (wave >> 1) * 64;  // wave row offset in 128-tile
  const int wc = (wave & 1) * 64;   // wave col offset
  const int ri = blockIdx.x >> 5;   // row tile 0..63
  const int cj = blockIdx.x & 31;   // col chunk 0..31
  const int row_base = ri * BM;

  float rowsum[4][4];  // [ti][reg] ; row = wr + ti*16 + lquad*4 + reg
  #pragma unroll
  for (int ti = 0; ti < 4; ++ti)
    #pragma unroll
    for (int r = 0; r < 4; ++r) rowsum[ti][r] = 0.f;

  for (int t = 0; t < 2; ++t) {
    const int jt = cj * 2 + t;
    const int col_base = jt * BN;

    floatx4 acc[4][4];
    #pragma unroll
    for (int ti = 0; ti < 4; ++ti)
      #pragma unroll
      for (int tj = 0; tj < 4; ++tj) acc[ti][tj] = floatx4{0.f, 0.f, 0.f, 0.f};

    for (int kb = 0; kb < D_DIM / BK; ++kb) {
      __syncthreads();  // previous iteration's LDS reads done before overwrite
      #pragma unroll
      for (int it = 0; it < 4; ++it) {
        const int s  = it * 256 + tid;        // LDS chunk slot, lane-contig
        const int m  = s >> 3;                // 0..127
        const int kc = (s & 7) ^ (m & 7);     // swizzled k-chunk from global
        const bf16* ga = zn + (size_t)(row_base + m) * D_DIM + kb * BK + kc * 8;
        const bf16* gb = zn + (size_t)(col_base + m) * D_DIM + kb * BK + kc * 8;
        __builtin_amdgcn_global_load_lds(
            (const __attribute__((address_space(1))) unsigned int*)ga,
            (__attribute__((address_space(3))) unsigned int*)&As[s * 8],
            16, 0, 0);
        __builtin_amdgcn_global_load_lds(
            (const __attribute__((address_space(1))) unsigned int*)gb,
            (__attribute__((address_space(3))) unsigned int*)&Bs[s * 8],
            16, 0, 0);
      }
      __syncthreads();  // implies vmcnt(0): staging visible

      #pragma unroll
      for (int ks = 0; ks < BK; ks += 32) {
        const int kc = (ks >> 3) + lquad;     // k-chunk this lane reads
        bf16x8 af[4], bfr[4];
        #pragma unroll
        for (int ti = 0; ti < 4; ++ti) {
          const int m = wr + ti * 16 + lcol;
          af[ti] = *(const bf16x8*)&As[(m * 8 + (kc ^ sw)) * 8];
        }
        #pragma unroll
        for (int tj = 0; tj < 4; ++tj) {
          const int m = wc + tj * 16 + lcol;
          bfr[tj] = *(const bf16x8*)&Bs[(m * 8 + (kc ^ sw)) * 8];
        }
        #pragma unroll
        for (int ti = 0; ti < 4; ++ti)
          #pragma unroll
          for (int tj = 0; tj < 4; ++tj)
            acc[ti][tj] = __builtin_amdgcn_mfma_f32_16x16x32_bf16(
                af[ti], bfr[tj], acc[ti][tj], 0, 0, 0);
      }
    }

    // epilogue: e = exp(sim/T) = exp(2*dot) = 2^(v * 2/ln2)
    const int dri = ri - jt;
    const bool diag = (dri == 0);
    const bool posT = (dri == 32) || (dri == -32);
    #pragma unroll
    for (int ti = 0; ti < 4; ++ti) {
      #pragma unroll
      for (int tj = 0; tj < 4; ++tj) {
        #pragma unroll
        for (int r = 0; r < 4; ++r) {
          const float v = acc[ti][tj][r];
          float e = exp2f(v * 2.8853900817779268f);
          if (diag || posT) {
            const int rrow = wr + ti * 16 + lquad * 4 + r;
            const int rcol = wc + tj * 16 + lcol;
            if (rrow == rcol) {
              if (diag) e = 0.f;                          // mask self
              else pos[row_base + rrow] = 2.0f * v;       // positive sim
            }
          }
          rowsum[ti][r] += e;
        }
      }
    }
  }

  // reduce the 16 col-lanes, then 1 atomic per row per wave
  #pragma unroll
  for (int ti = 0; ti < 4; ++ti) {
    #pragma unroll
    for (int r = 0; r < 4; ++r) {
      float s = rowsum[ti][r];
      s += __shfl_xor(s, 1);
      s += __shfl_xor(s, 2);
      s += __shfl_xor(s, 4);
      s += __shfl_xor(s, 8);
      if (lcol == 0) {
        const int grow = row_base + wr + ti * 16 + lquad * 4 + r;
        atomicAdd(&sumexp[grow], s);
      }
    }
  }
}

// ------------------------------------------------- finalize + mean (1 block)
// loss_i = log(sumexp_i) - pos_i ; out = mean(loss)
__global__ __launch_bounds__(1024) void reduce_kernel(
    const float* __restrict__ sumexp, const float* __restrict__ pos,
    float* __restrict__ out) {
  __shared__ float ws[16];
  const int tid = threadIdx.x;
  float s = 0.f;
  for (int k = tid; k < N_ROWS; k += 1024) s += __logf(sumexp[k]) - pos[k];
  #pragma unroll
  for (int m = 1; m < 64; m <<= 1) s += __shfl_xor(s, m);
  const int wave = tid >> 6, lane = tid & 63;
  if (lane == 0) ws[wave] = s;
  __syncthreads();
  if (wave == 0) {
    float t = (lane < 16) ? ws[lane] : 0.f;
    #pragma unroll
    for (int m = 1; m < 16; m <<= 1) t += __shfl_xor(t, m);
    if (lane == 0) out[0] = t * (1.0f / N_ROWS);
  }
}

extern "C" void kernel_launch(void* const* d_in, const int* in_sizes, int n_in,
                              void* d_out, int out_size, void* d_ws,
                              size_t ws_size, hipStream_t stream) {
  const float* z_i = (const float*)d_in[0];
  const float* z_j = (const float*)d_in[1];
  float* out = (float*)d_out;

  // workspace layout: zn (4 MB bf16) | sumexp (32 KB) | pos (32 KB)
  bf16* zn = (bf16*)d_ws;
  float* sumexp = (float*)((char*)d_ws + (size_t)N_ROWS * D_DIM * sizeof(bf16));
  float* pos = sumexp + N_ROWS;

  normalize_kernel<<<N_ROWS / 4, 256, 0, stream>>>(z_i, z_j, zn, sumexp);
  simexp_kernel<<<(N_ROWS / BM) * (N_ROWS / BN / 2), 256, 0, stream>>>(zn, sumexp, pos);
  reduce_kernel<<<1, 1024, 0, stream>>>(sumexp, pos, out);
}

// Round 3
// 129.905 us; speedup vs baseline: 1.2127x; 1.2127x over previous
//
#include <hip/hip_runtime.h>
#include <hip/hip_bf16.h>
#include <stdint.h>
#include <stddef.h>

// NT-Xent loss, B=4096, D=256, N=8192, T=0.5.
// normalize(+zero sumexp) -> fused ZZ^T GEMM + exp row-sum + positive capture
// -> 1-block finalize/mean. No NxN materialization.

#define B_ROWS 4096
#define D_DIM  256
#define N_ROWS 8192
#define BM 128
#define BN 128
#define BK 64

typedef __bf16 bf16;
typedef bf16  bf16x8  __attribute__((ext_vector_type(8)));
typedef bf16  bf16x4  __attribute__((ext_vector_type(4)));
typedef float floatx4 __attribute__((ext_vector_type(4)));

// ---------------------------------------------------------------- normalize
// One wave per row: 256 fp32 -> L2-normalized bf16. Also zeroes sumexp[row].
__global__ __launch_bounds__(256) void normalize_kernel(
    const float* __restrict__ z_i, const float* __restrict__ z_j,
    bf16* __restrict__ zn, float* __restrict__ sumexp) {
  const int wave = threadIdx.x >> 6;
  const int lane = threadIdx.x & 63;
  const int row  = blockIdx.x * 4 + wave;
  const float* src = (row < B_ROWS) ? (z_i + (size_t)row * D_DIM)
                                    : (z_j + (size_t)(row - B_ROWS) * D_DIM);
  float4 v = ((const float4*)src)[lane];
  float ss = v.x * v.x + v.y * v.y + v.z * v.z + v.w * v.w;
  #pragma unroll
  for (int m = 1; m < 64; m <<= 1) ss += __shfl_xor(ss, m);
  const float rn = rsqrtf(ss);
  bf16x4 o;
  o[0] = (bf16)(v.x * rn);
  o[1] = (bf16)(v.y * rn);
  o[2] = (bf16)(v.z * rn);
  o[3] = (bf16)(v.w * rn);
  ((bf16x4*)(zn + (size_t)row * D_DIM))[lane] = o;
  if (lane == 0) sumexp[row] = 0.f;
}

// ------------------------------------------------------- fused sim+exp+sum
// Grid: 64 row-tiles x 32 col-chunks (2 j-tiles each) = 2048 blocks.
// 128x128 tile, 4 waves (2x2), 4x4 frags of 16x16x32 bf16 MFMA, BK=64,
// global_load_lds width=16 with XOR-swizzled LDS layout (bank-conflict-free,
// verified R2: SQ_LDS_BANK_CONFLICT 1.26e7 -> 0): chunk (m, kc) of 8 bf16
// lives at slot m*8 + (kc ^ (m&7)); swizzle applied on the GLOBAL source
// address since global_load_lds forces dest = base + lane*16.
// launch_bounds (256,2): (256,4) in R2 capped VGPRs at 64 -> acc[4][4]
// spilled to scratch (FETCH+WRITE 373 MB, dur 56->102 us). At ~96-128 VGPR
// the HW occupancy limit is ~5 blocks/CU anyway (LDS 160/32=5).
__global__ __launch_bounds__(256, 2) void simexp_kernel(
    const bf16* __restrict__ zn, float* __restrict__ sumexp,
    float* __restrict__ pos) {
  __shared__ __align__(16) bf16 As[BM * BK];
  __shared__ __align__(16) bf16 Bs[BN * BK];

  const int tid   = threadIdx.x;
  const int wave  = tid >> 6;
  const int lane  = tid & 63;
  const int lcol  = lane & 15;   // MFMA: A row / B col / C col
  const int lquad = lane >> 4;   // MFMA: k-group / C row-group
  const int sw    = lcol & 7;    // read-side swizzle key (== m&7)
  const int wr = (wave >> 1) * 64;  // wave row offset in 128-tile
  const int wc = (wave & 1) * 64;   // wave col offset
  const int ri = blockIdx.x >> 5;   // row tile 0..63
  const int cj = blockIdx.x & 31;   // col chunk 0..31
  const int row_base = ri * BM;

  float rowsum[4][4];  // [ti][reg] ; row = wr + ti*16 + lquad*4 + reg
  #pragma unroll
  for (int ti = 0; ti < 4; ++ti)
    #pragma unroll
    for (int r = 0; r < 4; ++r) rowsum[ti][r] = 0.f;

  for (int t = 0; t < 2; ++t) {
    const int jt = cj * 2 + t;
    const int col_base = jt * BN;

    floatx4 acc[4][4];
    #pragma unroll
    for (int ti = 0; ti < 4; ++ti)
      #pragma unroll
      for (int tj = 0; tj < 4; ++tj) acc[ti][tj] = floatx4{0.f, 0.f, 0.f, 0.f};

    for (int kb = 0; kb < D_DIM / BK; ++kb) {
      __syncthreads();  // previous iteration's LDS reads done before overwrite
      #pragma unroll
      for (int it = 0; it < 4; ++it) {
        const int s  = it * 256 + tid;        // LDS chunk slot, lane-contig
        const int m  = s >> 3;                // 0..127
        const int kc = (s & 7) ^ (m & 7);     // swizzled k-chunk from global
        const bf16* ga = zn + (size_t)(row_base + m) * D_DIM + kb * BK + kc * 8;
        const bf16* gb = zn + (size_t)(col_base + m) * D_DIM + kb * BK + kc * 8;
        __builtin_amdgcn_global_load_lds(
            (const __attribute__((address_space(1))) unsigned int*)ga,
            (__attribute__((address_space(3))) unsigned int*)&As[s * 8],
            16, 0, 0);
        __builtin_amdgcn_global_load_lds(
            (const __attribute__((address_space(1))) unsigned int*)gb,
            (__attribute__((address_space(3))) unsigned int*)&Bs[s * 8],
            16, 0, 0);
      }
      __syncthreads();  // implies vmcnt(0): staging visible

      #pragma unroll
      for (int ks = 0; ks < BK; ks += 32) {
        const int kc = (ks >> 3) + lquad;     // k-chunk this lane reads
        bf16x8 af[4], bfr[4];
        #pragma unroll
        for (int ti = 0; ti < 4; ++ti) {
          const int m = wr + ti * 16 + lcol;
          af[ti] = *(const bf16x8*)&As[(m * 8 + (kc ^ sw)) * 8];
        }
        #pragma unroll
        for (int tj = 0; tj < 4; ++tj) {
          const int m = wc + tj * 16 + lcol;
          bfr[tj] = *(const bf16x8*)&Bs[(m * 8 + (kc ^ sw)) * 8];
        }
        #pragma unroll
        for (int ti = 0; ti < 4; ++ti)
          #pragma unroll
          for (int tj = 0; tj < 4; ++tj)
            acc[ti][tj] = __builtin_amdgcn_mfma_f32_16x16x32_bf16(
                af[ti], bfr[tj], acc[ti][tj], 0, 0, 0);
      }
    }

    // epilogue: e = exp(sim/T) = exp(2*dot) = 2^(v * 2/ln2)
    const int dri = ri - jt;
    const bool diag = (dri == 0);
    const bool posT = (dri == 32) || (dri == -32);
    #pragma unroll
    for (int ti = 0; ti < 4; ++ti) {
      #pragma unroll
      for (int tj = 0; tj < 4; ++tj) {
        #pragma unroll
        for (int r = 0; r < 4; ++r) {
          const float v = acc[ti][tj][r];
          float e = exp2f(v * 2.8853900817779268f);
          if (diag || posT) {
            const int rrow = wr + ti * 16 + lquad * 4 + r;
            const int rcol = wc + tj * 16 + lcol;
            if (rrow == rcol) {
              if (diag) e = 0.f;                          // mask self
              else pos[row_base + rrow] = 2.0f * v;       // positive sim
            }
          }
          rowsum[ti][r] += e;
        }
      }
    }
  }

  // reduce the 16 col-lanes, then 1 atomic per row per wave
  #pragma unroll
  for (int ti = 0; ti < 4; ++ti) {
    #pragma unroll
    for (int r = 0; r < 4; ++r) {
      float s = rowsum[ti][r];
      s += __shfl_xor(s, 1);
      s += __shfl_xor(s, 2);
      s += __shfl_xor(s, 4);
      s += __shfl_xor(s, 8);
      if (lcol == 0) {
        const int grow = row_base + wr + ti * 16 + lquad * 4 + r;
        atomicAdd(&sumexp[grow], s);
      }
    }
  }
}

// ------------------------------------------------- finalize + mean (1 block)
// loss_i = log(sumexp_i) - pos_i ; out = mean(loss)
__global__ __launch_bounds__(1024) void reduce_kernel(
    const float* __restrict__ sumexp, const float* __restrict__ pos,
    float* __restrict__ out) {
  __shared__ float ws[16];
  const int tid = threadIdx.x;
  float s = 0.f;
  for (int k = tid; k < N_ROWS; k += 1024) s += __logf(sumexp[k]) - pos[k];
  #pragma unroll
  for (int m = 1; m < 64; m <<= 1) s += __shfl_xor(s, m);
  const int wave = tid >> 6, lane = tid & 63;
  if (lane == 0) ws[wave] = s;
  __syncthreads();
  if (wave == 0) {
    float t = (lane < 16) ? ws[lane] : 0.f;
    #pragma unroll
    for (int m = 1; m < 16; m <<= 1) t += __shfl_xor(t, m);
    if (lane == 0) out[0] = t * (1.0f / N_ROWS);
  }
}

extern "C" void kernel_launch(void* const* d_in, const int* in_sizes, int n_in,
                              void* d_out, int out_size, void* d_ws,
                              size_t ws_size, hipStream_t stream) {
  const float* z_i = (const float*)d_in[0];
  const float* z_j = (const float*)d_in[1];
  float* out = (float*)d_out;

  // workspace layout: zn (4 MB bf16) | sumexp (32 KB) | pos (32 KB)
  bf16* zn = (bf16*)d_ws;
  float* sumexp = (float*)((char*)d_ws + (size_t)N_ROWS * D_DIM * sizeof(bf16));
  float* pos = sumexp + N_ROWS;

  normalize_kernel<<<N_ROWS / 4, 256, 0, stream>>>(z_i, z_j, zn, sumexp);
  simexp_kernel<<<(N_ROWS / BM) * (N_ROWS / BN / 2), 256, 0, stream>>>(zn, sumexp, pos);
  reduce_kernel<<<1, 1024, 0, stream>>>(sumexp, pos, out);
}

// Round 4
// 112.809 us; speedup vs baseline: 1.3964x; 1.1516x over previous
//
#include <hip/hip_runtime.h>
#include <hip/hip_bf16.h>
#include <stdint.h>
#include <stddef.h>

// NT-Xent loss, B=4096, D=256, N=8192, T=0.5.
// normalize(+zero sumexp) -> fused ZZ^T GEMM + exp row-sum + positive capture
// -> 1-block finalize/mean. No NxN materialization.
//
// R4 structure: K-loop eliminated. A-fragments (64 rows x full D per wave)
// are register-resident for the whole block (af[4][8] = 128 VGPRs, loaded
// once from L2). B is full-depth in LDS (BN=64 -> 32 KB), double-buffered
// (64 KB total, 2 blocks/CU). One barrier per j-tile; B(t+1) prefetch is
// issued right after the barrier and drains at the NEXT barrier ~2500 cyc
// later -> vmcnt(0) stall ~0. LDS read demand 0.25 KB/MFMA (bfr only) vs
// 85 B/cyc ceiling -> LDS no longer the bottleneck (R1-R3 were 0.5 KB/MFMA).

#define B_ROWS 4096
#define D_DIM  256
#define N_ROWS 8192
#define BM 128
#define BN 64

typedef __bf16 bf16;
typedef bf16  bf16x8  __attribute__((ext_vector_type(8)));
typedef bf16  bf16x4  __attribute__((ext_vector_type(4)));
typedef float floatx4 __attribute__((ext_vector_type(4)));

// ---------------------------------------------------------------- normalize
// One wave per row: 256 fp32 -> L2-normalized bf16. Also zeroes sumexp[row].
__global__ __launch_bounds__(256) void normalize_kernel(
    const float* __restrict__ z_i, const float* __restrict__ z_j,
    bf16* __restrict__ zn, float* __restrict__ sumexp) {
  const int wave = threadIdx.x >> 6;
  const int lane = threadIdx.x & 63;
  const int row  = blockIdx.x * 4 + wave;
  const float* src = (row < B_ROWS) ? (z_i + (size_t)row * D_DIM)
                                    : (z_j + (size_t)(row - B_ROWS) * D_DIM);
  float4 v = ((const float4*)src)[lane];
  float ss = v.x * v.x + v.y * v.y + v.z * v.z + v.w * v.w;
  #pragma unroll
  for (int m = 1; m < 64; m <<= 1) ss += __shfl_xor(ss, m);
  const float rn = rsqrtf(ss);
  bf16x4 o;
  o[0] = (bf16)(v.x * rn);
  o[1] = (bf16)(v.y * rn);
  o[2] = (bf16)(v.z * rn);
  o[3] = (bf16)(v.w * rn);
  ((bf16x4*)(zn + (size_t)row * D_DIM))[lane] = o;
  if (lane == 0) sumexp[row] = 0.f;
}

// ------------------------------------------------------- fused sim+exp+sum
// Grid: 64 row-tiles x 8 col-chunks = 512 blocks (2/CU). Each block: rows
// [ri*128, +128), j-tiles jt = cj*16 .. +15 (64 cols each). 4 waves in 2x2:
// wave covers 64 rows x 32 cols = 4x2 frags of 16x16x32 bf16 MFMA.
// LDS B layout XOR-swizzled (conflict-free, verified R2/R3): 16B chunk of
// row n, k-chunk kc lives at slot n*32 + ((kc&24) | ((kc&7)^(n&7))); the
// swizzle is applied on the GLOBAL source address (global_load_lds forces
// dest = base + lane*16). Read side: n&7 == lcol&7 so key is lcol&7.
__global__ __launch_bounds__(256, 2) void simexp_kernel(
    const bf16* __restrict__ zn, float* __restrict__ sumexp,
    float* __restrict__ pos) {
  __shared__ __align__(16) bf16 Bs[2][BN * D_DIM];  // 2 x 32 KB

  const int tid   = threadIdx.x;
  const int wave  = tid >> 6;
  const int lane  = tid & 63;
  const int lcol  = lane & 15;   // MFMA: A row / B col / C col
  const int lquad = lane >> 4;   // MFMA: k-group / C row-group
  const int wr = (wave >> 1) * 64;  // wave row offset in 128
  const int wc = (wave & 1) * 32;   // wave col offset in 64
  const int ri = blockIdx.x >> 3;   // row tile 0..63
  const int cj = blockIdx.x & 7;    // col chunk 0..7
  const int row_base = ri * BM;
  const int jt0 = cj * 16;

  // A fragments, register-resident for the whole block.
  // af[ti][kq]: row = row_base+wr+ti*16+lcol, k = kq*32 + lquad*8 .. +7
  bf16x8 af[4][8];
  #pragma unroll
  for (int ti = 0; ti < 4; ++ti) {
    const bf16* arow =
        zn + (size_t)(row_base + wr + ti * 16 + lcol) * D_DIM + lquad * 8;
    #pragma unroll
    for (int kq = 0; kq < 8; ++kq)
      af[ti][kq] = *(const bf16x8*)(arow + kq * 32);
  }

  float rowsum[4][4];  // [ti][r]; row = wr + ti*16 + lquad*4 + r
  #pragma unroll
  for (int ti = 0; ti < 4; ++ti)
    #pragma unroll
    for (int r = 0; r < 4; ++r) rowsum[ti][r] = 0.f;

  // stage B j-tile jt into buffer buf (8 global_load_lds x 16 B per thread)
  auto stageB = [&](int buf, int jt) {
    const bf16* src = zn + (size_t)jt * BN * D_DIM;
    #pragma unroll
    for (int it = 0; it < 8; ++it) {
      const int s   = it * 256 + tid;   // chunk slot 0..2047
      const int n   = s >> 5;           // row 0..63
      const int kcs = s & 31;           // swizzled k-chunk slot
      const int kc  = (kcs & 24) | ((kcs & 7) ^ (n & 7));
      __builtin_amdgcn_global_load_lds(
          (const __attribute__((address_space(1))) unsigned int*)
              (src + (size_t)n * D_DIM + kc * 8),
          (__attribute__((address_space(3))) unsigned int*)&Bs[buf][s * 8],
          16, 0, 0);
    }
  };

  stageB(0, jt0);

  for (int t = 0; t < 16; ++t) {
    const int jt = jt0 + t;
    __syncthreads();  // drains prefetch for buf[t&1]; fences buf[(t+1)&1] reads
    if (t < 15) stageB((t + 1) & 1, jt + 1);

    floatx4 acc[4][2];
    #pragma unroll
    for (int ti = 0; ti < 4; ++ti)
      #pragma unroll
      for (int tj = 0; tj < 2; ++tj) acc[ti][tj] = floatx4{0.f, 0.f, 0.f, 0.f};

    const bf16* bbase = &Bs[t & 1][0];
    #pragma unroll
    for (int kq = 0; kq < 8; ++kq) {
      const int kc  = kq * 4 + lquad;
      const int kcs = (kc & 24) | ((kc & 7) ^ (lcol & 7));
      bf16x8 bfr[2];
      #pragma unroll
      for (int tj = 0; tj < 2; ++tj) {
        const int n = wc + tj * 16 + lcol;
        bfr[tj] = *(const bf16x8*)(bbase + n * D_DIM + kcs * 8);
      }
      #pragma unroll
      for (int ti = 0; ti < 4; ++ti)
        #pragma unroll
        for (int tj = 0; tj < 2; ++tj)
          acc[ti][tj] = __builtin_amdgcn_mfma_f32_16x16x32_bf16(
              af[ti][kq], bfr[tj], acc[ti][tj], 0, 0, 0);
    }

    // epilogue: e = exp(sim/T) = exp(2*dot) = 2^(v * 2/ln2)
    const int jth = jt >> 1;  // 128-granular col tile
    const bool special = (jth == ri) || (jth == ri + 32) || (jth + 32 == ri);
    const int col_base = jt * BN;
    #pragma unroll
    for (int ti = 0; ti < 4; ++ti) {
      #pragma unroll
      for (int tj = 0; tj < 2; ++tj) {
        #pragma unroll
        for (int r = 0; r < 4; ++r) {
          const float v = acc[ti][tj][r];
          float e = exp2f(v * 2.8853900817779268f);
          if (special) {
            const int rg = row_base + wr + ti * 16 + lquad * 4 + r;
            const int cg = col_base + wc + tj * 16 + lcol;
            if (cg == rg) e = 0.f;                       // mask self
            else if (cg == rg + B_ROWS || cg + B_ROWS == rg)
              pos[rg] = 2.0f * v;                        // positive sim
          }
          rowsum[ti][r] += e;
        }
      }
    }
  }

  // reduce the 16 col-lanes, then 1 atomic per row per wave
  #pragma unroll
  for (int ti = 0; ti < 4; ++ti) {
    #pragma unroll
    for (int r = 0; r < 4; ++r) {
      float s = rowsum[ti][r];
      s += __shfl_xor(s, 1);
      s += __shfl_xor(s, 2);
      s += __shfl_xor(s, 4);
      s += __shfl_xor(s, 8);
      if (lcol == 0) {
        const int grow = row_base + wr + ti * 16 + lquad * 4 + r;
        atomicAdd(&sumexp[grow], s);
      }
    }
  }
}

// ------------------------------------------------- finalize + mean (1 block)
// loss_i = log(sumexp_i) - pos_i ; out = mean(loss)
__global__ __launch_bounds__(1024) void reduce_kernel(
    const float* __restrict__ sumexp, const float* __restrict__ pos,
    float* __restrict__ out) {
  __shared__ float ws[16];
  const int tid = threadIdx.x;
  float s = 0.f;
  for (int k = tid; k < N_ROWS; k += 1024) s += __logf(sumexp[k]) - pos[k];
  #pragma unroll
  for (int m = 1; m < 64; m <<= 1) s += __shfl_xor(s, m);
  const int wave = tid >> 6, lane = tid & 63;
  if (lane == 0) ws[wave] = s;
  __syncthreads();
  if (wave == 0) {
    float t = (lane < 16) ? ws[lane] : 0.f;
    #pragma unroll
    for (int m = 1; m < 16; m <<= 1) t += __shfl_xor(t, m);
    if (lane == 0) out[0] = t * (1.0f / N_ROWS);
  }
}

extern "C" void kernel_launch(void* const* d_in, const int* in_sizes, int n_in,
                              void* d_out, int out_size, void* d_ws,
                              size_t ws_size, hipStream_t stream) {
  const float* z_i = (const float*)d_in[0];
  const float* z_j = (const float*)d_in[1];
  float* out = (float*)d_out;

  // workspace layout: zn (4 MB bf16) | sumexp (32 KB) | pos (32 KB)
  bf16* zn = (bf16*)d_ws;
  float* sumexp = (float*)((char*)d_ws + (size_t)N_ROWS * D_DIM * sizeof(bf16));
  float* pos = sumexp + N_ROWS;

  normalize_kernel<<<N_ROWS / 4, 256, 0, stream>>>(z_i, z_j, zn, sumexp);
  simexp_kernel<<<(N_ROWS / BM) * 8, 256, 0, stream>>>(zn, sumexp, pos);
  reduce_kernel<<<1, 1024, 0, stream>>>(sumexp, pos, out);
}

// Round 5
// 112.261 us; speedup vs baseline: 1.4033x; 1.0049x over previous
//
#include <hip/hip_runtime.h>
#include <hip/hip_bf16.h>
#include <stdint.h>
#include <stddef.h>

// NT-Xent loss, B=4096, D=256, N=8192, T=0.5.
// normalize(+zero sumexp) -> fused ZZ^T GEMM + exp row-sum + positive capture
// -> 1-block finalize/mean. No NxN materialization.
//
// R5: R4 structure (K-loop eliminated, A register-resident, B full-depth in
// LDS double-buffered, one barrier per j-tile) + PIN the A-fragments with an
// empty asm("+v") after loading. R4's compiler rematerialized af from global
// every t-iteration (VGPR_Count=120 < 128 needed for af alone) -> L2-latency
// bound, MfmaUtil 23%. The asm makes af opaque: no rematerialization.

#define B_ROWS 4096
#define D_DIM  256
#define N_ROWS 8192
#define BM 128
#define BN 64

typedef __bf16 bf16;
typedef bf16  bf16x8  __attribute__((ext_vector_type(8)));
typedef bf16  bf16x4  __attribute__((ext_vector_type(4)));
typedef float floatx4 __attribute__((ext_vector_type(4)));

// ---------------------------------------------------------------- normalize
// One wave per row: 256 fp32 -> L2-normalized bf16. Also zeroes sumexp[row].
__global__ __launch_bounds__(256) void normalize_kernel(
    const float* __restrict__ z_i, const float* __restrict__ z_j,
    bf16* __restrict__ zn, float* __restrict__ sumexp) {
  const int wave = threadIdx.x >> 6;
  const int lane = threadIdx.x & 63;
  const int row  = blockIdx.x * 4 + wave;
  const float* src = (row < B_ROWS) ? (z_i + (size_t)row * D_DIM)
                                    : (z_j + (size_t)(row - B_ROWS) * D_DIM);
  float4 v = ((const float4*)src)[lane];
  float ss = v.x * v.x + v.y * v.y + v.z * v.z + v.w * v.w;
  #pragma unroll
  for (int m = 1; m < 64; m <<= 1) ss += __shfl_xor(ss, m);
  const float rn = rsqrtf(ss);
  bf16x4 o;
  o[0] = (bf16)(v.x * rn);
  o[1] = (bf16)(v.y * rn);
  o[2] = (bf16)(v.z * rn);
  o[3] = (bf16)(v.w * rn);
  ((bf16x4*)(zn + (size_t)row * D_DIM))[lane] = o;
  if (lane == 0) sumexp[row] = 0.f;
}

// ------------------------------------------------------- fused sim+exp+sum
// Grid: 64 row-tiles x 8 col-chunks = 512 blocks (2/CU, exact residency).
// Block: rows [ri*128,+128), 16 j-tiles of 64 cols. 4 waves in 2x2; wave =
// 64 rows x 32 cols = 4x2 frags of 16x16x32 bf16 MFMA, full-D accumulate
// (8 chained MFMAs per frag, no K-loop barriers).
// LDS B layout XOR-swizzled (conflict-free, verified R2/R3): 16B chunk of
// row n, k-chunk kc lives at slot n*32 + ((kc&24) | ((kc&7)^(n&7))); swizzle
// applied on the GLOBAL source address (global_load_lds forces dest =
// base + lane*16). Read-side key: n&7 == lcol&7.
__global__ __launch_bounds__(256, 2) void simexp_kernel(
    const bf16* __restrict__ zn, float* __restrict__ sumexp,
    float* __restrict__ pos) {
  __shared__ __align__(16) bf16 Bs[2][BN * D_DIM];  // 2 x 32 KB

  const int tid   = threadIdx.x;
  const int wave  = tid >> 6;
  const int lane  = tid & 63;
  const int lcol  = lane & 15;   // MFMA: A row / B col / C col
  const int lquad = lane >> 4;   // MFMA: k-group / C row-group
  const int wr = (wave >> 1) * 64;  // wave row offset in 128
  const int wc = (wave & 1) * 32;   // wave col offset in 64
  const int ri = blockIdx.x >> 3;   // row tile 0..63
  const int cj = blockIdx.x & 7;    // col chunk 0..7
  const int row_base = ri * BM;
  const int jt0 = cj * 16;

  // stage B j-tile jt into buffer buf (8 global_load_lds x 16 B per thread)
  auto stageB = [&](int buf, int jt) {
    const bf16* src = zn + (size_t)jt * BN * D_DIM;
    #pragma unroll
    for (int it = 0; it < 8; ++it) {
      const int s   = it * 256 + tid;   // chunk slot 0..2047
      const int n   = s >> 5;           // row 0..63
      const int kcs = s & 31;           // swizzled k-chunk slot
      const int kc  = (kcs & 24) | ((kcs & 7) ^ (n & 7));
      __builtin_amdgcn_global_load_lds(
          (const __attribute__((address_space(1))) unsigned int*)
              (src + (size_t)n * D_DIM + kc * 8),
          (__attribute__((address_space(3))) unsigned int*)&Bs[buf][s * 8],
          16, 0, 0);
    }
  };

  stageB(0, jt0);  // first prefetch in flight while A loads below

  // A fragments, register-resident for the whole block (128 VGPRs).
  // af[ti][kq]: row = row_base+wr+ti*16+lcol, k = kq*32 + lquad*8 .. +7
  floatx4 af[4][8];
  #pragma unroll
  for (int ti = 0; ti < 4; ++ti) {
    const bf16* arow =
        zn + (size_t)(row_base + wr + ti * 16 + lcol) * D_DIM + lquad * 8;
    #pragma unroll
    for (int kq = 0; kq < 8; ++kq)
      af[ti][kq] = *(const floatx4*)(arow + kq * 32);
  }
  // Pin: opaque to the compiler -> cannot rematerialize from global (R4 bug).
  #pragma unroll
  for (int ti = 0; ti < 4; ++ti)
    #pragma unroll
    for (int kq = 0; kq < 8; ++kq)
      asm volatile("" : "+v"(af[ti][kq]));

  float rowsum[4][4];  // [ti][r]; row = wr + ti*16 + lquad*4 + r
  #pragma unroll
  for (int ti = 0; ti < 4; ++ti)
    #pragma unroll
    for (int r = 0; r < 4; ++r) rowsum[ti][r] = 0.f;

  for (int t = 0; t < 16; ++t) {
    const int jt = jt0 + t;
    __syncthreads();  // drains prefetch for buf[t&1]; fences buf[(t+1)&1] reads
    if (t < 15) stageB((t + 1) & 1, jt + 1);

    floatx4 acc[4][2];
    #pragma unroll
    for (int ti = 0; ti < 4; ++ti)
      #pragma unroll
      for (int tj = 0; tj < 2; ++tj) acc[ti][tj] = floatx4{0.f, 0.f, 0.f, 0.f};

    const bf16* bbase = &Bs[t & 1][0];
    #pragma unroll
    for (int kq = 0; kq < 8; ++kq) {
      const int kc  = kq * 4 + lquad;
      const int kcs = (kc & 24) | ((kc & 7) ^ (lcol & 7));
      bf16x8 bfr[2];
      #pragma unroll
      for (int tj = 0; tj < 2; ++tj) {
        const int n = wc + tj * 16 + lcol;
        bfr[tj] = *(const bf16x8*)(bbase + n * D_DIM + kcs * 8);
      }
      #pragma unroll
      for (int ti = 0; ti < 4; ++ti)
        #pragma unroll
        for (int tj = 0; tj < 2; ++tj)
          acc[ti][tj] = __builtin_amdgcn_mfma_f32_16x16x32_bf16(
              __builtin_bit_cast(bf16x8, af[ti][kq]), bfr[tj], acc[ti][tj],
              0, 0, 0);
    }

    // epilogue: e = exp(sim/T) = exp(2*dot) = 2^(v * 2/ln2)
    const int jth = jt >> 1;  // 128-granular col tile
    const bool special = (jth == ri) || (jth == ri + 32) || (jth + 32 == ri);
    const int col_base = jt * BN;
    #pragma unroll
    for (int ti = 0; ti < 4; ++ti) {
      #pragma unroll
      for (int tj = 0; tj < 2; ++tj) {
        #pragma unroll
        for (int r = 0; r < 4; ++r) {
          const float v = acc[ti][tj][r];
          float e = exp2f(v * 2.8853900817779268f);
          if (special) {
            const int rg = row_base + wr + ti * 16 + lquad * 4 + r;
            const int cg = col_base + wc + tj * 16 + lcol;
            if (cg == rg) e = 0.f;                       // mask self
            else if (cg == rg + B_ROWS || cg + B_ROWS == rg)
              pos[rg] = 2.0f * v;                        // positive sim
          }
          rowsum[ti][r] += e;
        }
      }
    }
  }

  // reduce the 16 col-lanes, then 1 atomic per row per wave
  #pragma unroll
  for (int ti = 0; ti < 4; ++ti) {
    #pragma unroll
    for (int r = 0; r < 4; ++r) {
      float s = rowsum[ti][r];
      s += __shfl_xor(s, 1);
      s += __shfl_xor(s, 2);
      s += __shfl_xor(s, 4);
      s += __shfl_xor(s, 8);
      if (lcol == 0) {
        const int grow = row_base + wr + ti * 16 + lquad * 4 + r;
        atomicAdd(&sumexp[grow], s);
      }
    }
  }
}

// ------------------------------------------------- finalize + mean (1 block)
// loss_i = log(sumexp_i) - pos_i ; out = mean(loss)
__global__ __launch_bounds__(1024) void reduce_kernel(
    const float* __restrict__ sumexp, const float* __restrict__ pos,
    float* __restrict__ out) {
  __shared__ float ws[16];
  const int tid = threadIdx.x;
  float s = 0.f;
  for (int k = tid; k < N_ROWS; k += 1024) s += __logf(sumexp[k]) - pos[k];
  #pragma unroll
  for (int m = 1; m < 64; m <<= 1) s += __shfl_xor(s, m);
  const int wave = tid >> 6, lane = tid & 63;
  if (lane == 0) ws[wave] = s;
  __syncthreads();
  if (wave == 0) {
    float t = (lane < 16) ? ws[lane] : 0.f;
    #pragma unroll
    for (int m = 1; m < 16; m <<= 1) t += __shfl_xor(t, m);
    if (lane == 0) out[0] = t * (1.0f / N_ROWS);
  }
}

extern "C" void kernel_launch(void* const* d_in, const int* in_sizes, int n_in,
                              void* d_out, int out_size, void* d_ws,
                              size_t ws_size, hipStream_t stream) {
  const float* z_i = (const float*)d_in[0];
  const float* z_j = (const float*)d_in[1];
  float* out = (float*)d_out;

  // workspace layout: zn (4 MB bf16) | sumexp (32 KB) | pos (32 KB)
  bf16* zn = (bf16*)d_ws;
  float* sumexp = (float*)((char*)d_ws + (size_t)N_ROWS * D_DIM * sizeof(bf16));
  float* pos = sumexp + N_ROWS;

  normalize_kernel<<<N_ROWS / 4, 256, 0, stream>>>(z_i, z_j, zn, sumexp);
  simexp_kernel<<<(N_ROWS / BM) * 8, 256, 0, stream>>>(zn, sumexp, pos);
  reduce_kernel<<<1, 1024, 0, stream>>>(sumexp, pos, out);
}